// Round 1
// baseline (500.976 us; speedup 1.0000x reference)
//
#include <hip/hip_runtime.h>
#include <cstdint>
#include <cstddef>

typedef __attribute__((ext_vector_type(8))) __bf16 bf16x8;
typedef __attribute__((ext_vector_type(4))) float f32x4;

__device__ __forceinline__ float sigm(float v) { return 1.0f / (1.0f + expf(-v)); }

__device__ __forceinline__ void async16(__bf16* lds, const __bf16* g) {
  __builtin_amdgcn_global_load_lds(
      (const __attribute__((address_space(1))) void*)g,
      (__attribute__((address_space(3))) void*)lds, 16, 0, 0);
}

// ---------------- convert fp32 -> bf16, 8 elems/thread ----------------
__global__ __launch_bounds__(256) void k_convert(const float* __restrict__ src,
                                                 __bf16* __restrict__ dst, int n8) {
  int i = blockIdx.x * 256 + threadIdx.x;
  if (i >= n8) return;
  const f32x4* s4 = (const f32x4*)src;
  f32x4 a = s4[2 * i], b = s4[2 * i + 1];
  bf16x8 o;
#pragma unroll
  for (int e = 0; e < 4; ++e) { o[e] = (__bf16)a[e]; o[4 + e] = (__bf16)b[e]; }
  ((bf16x8*)dst)[i] = o;
}

__global__ __launch_bounds__(256) void k_bcat(const float* __restrict__ bh,
                                              const float* __restrict__ bw,
                                              const float* __restrict__ bs,
                                              float* __restrict__ bcat) {
  int i = blockIdx.x * 256 + threadIdx.x;
  if (i >= 2304) return;
  bcat[i] = i < 768 ? bh[i] : (i < 1536 ? bw[i - 768] : bs[i - 1536]);
}

// ---------------- GEMM, BT layout (A: MxK K-contig, B: NxK K-contig) ----------------
// 128x128 tile, BK=32, 4 waves (2x2), each wave 64x64 = 4x4 mfma_f32_16x16x32_bf16.
// EPI 0: out_bf16 = gelu(acc + bias[col])           (h|w|s projection)
// EPI 1: out_bf16 = acc + bias[col]                 (mixall)
// EPI 2: out_f32  = g0*(acc + bias[col]) + g1*x     (proj + residual)
template <int EPI>
__global__ __launch_bounds__(256) void k_gemm(
    const __bf16* __restrict__ A, const __bf16* __restrict__ B,
    const float* __restrict__ bias, __bf16* __restrict__ outB,
    float* __restrict__ outF, const float* __restrict__ xres,
    const float* __restrict__ gatew, int N, int K) {
  __shared__ __bf16 lA[128 * 32];
  __shared__ __bf16 lB[128 * 32];
  const int tid = threadIdx.x;
  const int wave = tid >> 6, lane = tid & 63;
  const int nTn = N >> 7;
  const int tm = blockIdx.x / nTn, tn = blockIdx.x % nTn;
  const __bf16* Ag = A + (size_t)tm * 128 * K;
  const __bf16* Bg = B + (size_t)tn * 128 * K;
  const int srow = tid >> 2;
  const int scol = (tid & 3) << 3;
  const size_t sOff = (size_t)srow * K + scol;

  f32x4 acc[4][4];
#pragma unroll
  for (int m = 0; m < 4; ++m)
#pragma unroll
    for (int n = 0; n < 4; ++n) acc[m][n] = f32x4{0.f, 0.f, 0.f, 0.f};

  const int wr = wave >> 1, wc = wave & 1;
  const int rb = wr * 64 + (lane & 15);
  const int cb = wc * 64 + (lane & 15);
  const int kf = (lane >> 4) << 3;

  for (int k0 = 0; k0 < K; k0 += 32) {
    __syncthreads();  // protect LDS from previous iteration's readers
    async16(lA + wave * 512,        Ag + sOff + k0);
    async16(lA + 2048 + wave * 512, Ag + sOff + (size_t)64 * K + k0);
    async16(lB + wave * 512,        Bg + sOff + k0);
    async16(lB + 2048 + wave * 512, Bg + sOff + (size_t)64 * K + k0);
    __syncthreads();  // drains vmcnt (global_load_lds) before reads

    bf16x8 af[4], bfv[4];
#pragma unroll
    for (int m = 0; m < 4; ++m)
      af[m] = *(const bf16x8*)&lA[(rb + m * 16) * 32 + kf];
#pragma unroll
    for (int n = 0; n < 4; ++n)
      bfv[n] = *(const bf16x8*)&lB[(cb + n * 16) * 32 + kf];
#pragma unroll
    for (int m = 0; m < 4; ++m)
#pragma unroll
      for (int n = 0; n < 4; ++n)
        acc[m][n] = __builtin_amdgcn_mfma_f32_16x16x32_bf16(af[m], bfv[n], acc[m][n], 0, 0, 0);
  }

  // epilogue: C/D layout col=lane&15, row=(lane>>4)*4+reg  [learn_hip m89]
  const int orow = (lane >> 4) * 4;
  const int ocol = lane & 15;
  float g0 = 0.f, g1 = 0.f;
  if (EPI == 2) { g0 = gatew[0]; g1 = gatew[1]; }
#pragma unroll
  for (int m = 0; m < 4; ++m) {
#pragma unroll
    for (int n = 0; n < 4; ++n) {
#pragma unroll
      for (int r = 0; r < 4; ++r) {
        const int rg = tm * 128 + wr * 64 + m * 16 + orow + r;
        const int cg = tn * 128 + wc * 64 + n * 16 + ocol;
        float v = acc[m][n][r] + bias[cg];
        if (EPI == 0) {
          v = 0.5f * v * (1.0f + erff(v * 0.70710678118654752f));  // exact gelu
          outB[(size_t)rg * N + cg] = (__bf16)v;
        } else if (EPI == 1) {
          outB[(size_t)rg * N + cg] = (__bf16)v;
        } else {
          outF[(size_t)rg * N + cg] = g0 * v + g1 * xres[(size_t)rg * N + cg];
        }
      }
    }
  }
}

// ---------------- pooling: h2v (B,7), w2v (B,7), s1v (B,768) ----------------
// one block per batch b; hws row layout per pixel: [h(768) | w(768) | s(768)]
__global__ __launch_bounds__(256) void k_pool(const __bf16* __restrict__ hws,
                                              float* __restrict__ h2v,
                                              float* __restrict__ w2v,
                                              float* __restrict__ s1v) {
  const int b = blockIdx.x, t = threadIdx.x;
  const int lane = t & 63, wave = t >> 6;
  const size_t base = (size_t)b * 49 * 2304;
  float hloc[7], wloc[7];
#pragma unroll
  for (int i = 0; i < 7; ++i) { hloc[i] = 0.f; wloc[i] = 0.f; }
  float sacc[8], sacc2[8];
#pragma unroll
  for (int e = 0; e < 8; ++e) { sacc[e] = 0.f; sacc2[e] = 0.f; }

  // chunk roles per pixel (288 chunks of 8 bf16): t<96 -> h, 96..191 -> w,
  // 192..255 -> s chunks 0..63; threads 0..31 also take s chunks 64..95.
  const bool isH = t < 96, isW = (t >= 96 && t < 192);
  const int off1 = isH ? t * 8 : (isW ? 768 + (t - 96) * 8 : 1536 + (t - 192) * 8);
  const int off2 = 1536 + (64 + t) * 8;

#pragma unroll
  for (int p = 0; p < 49; ++p) {
    const int hi = p / 7, wi = p % 7;
    const __bf16* row = hws + base + (size_t)p * 2304;
    bf16x8 v = *(const bf16x8*)(row + off1);
    float s8 = 0.f;
#pragma unroll
    for (int e = 0; e < 8; ++e) s8 += (float)v[e];
    if (isH) hloc[hi] += s8;
    else if (isW) wloc[wi] += s8;
    else {
#pragma unroll
      for (int e = 0; e < 8; ++e) sacc[e] += (float)v[e];
    }
    if (t < 32) {
      bf16x8 v2 = *(const bf16x8*)(row + off2);
#pragma unroll
      for (int e = 0; e < 8; ++e) sacc2[e] += (float)v2[e];
    }
  }

  if (t >= 192) {
#pragma unroll
    for (int e = 0; e < 8; ++e)
      s1v[b * 768 + (t - 192) * 8 + e] = sacc[e] * (1.f / 49.f);
  }
  if (t < 32) {
#pragma unroll
    for (int e = 0; e < 8; ++e)
      s1v[b * 768 + 512 + t * 8 + e] = sacc2[e] * (1.f / 49.f);
  }

  __shared__ float red[4][14];
#pragma unroll
  for (int i = 0; i < 7; ++i) {
    float hv = hloc[i], wv = wloc[i];
#pragma unroll
    for (int s = 32; s; s >>= 1) { hv += __shfl_xor(hv, s); wv += __shfl_xor(wv, s); }
    if (lane == 0) { red[wave][i] = hv; red[wave][7 + i] = wv; }
  }
  __syncthreads();
  if (t < 7) {
    h2v[b * 7 + t] = (red[0][t] + red[1][t] + red[2][t] + red[3][t]) * (1.f / 5376.f);
  } else if (t >= 16 && t < 23) {
    const int i = t - 16;
    w2v[b * 7 + i] =
        (red[0][7 + i] + red[1][7 + i] + red[2][7 + i] + red[3][7 + i]) * (1.f / 5376.f);
  }
}

// ---------------- gates: g_h (B,7), g_hw (B,7), g_c (B,768) ----------------
__global__ __launch_bounds__(256) void k_gates(
    const float* __restrict__ h2v, const float* __restrict__ w2v,
    const float* __restrict__ s1v, const float* __restrict__ convH_w,
    const float* __restrict__ convH_b, const float* __restrict__ convH2_k,
    const float* __restrict__ convH2_b, const float* __restrict__ mixhw_k,
    const float* __restrict__ mixhw_b, const float* __restrict__ mixhw2_k,
    const float* __restrict__ mixhw2_b, const float* __restrict__ mixhws_k,
    const float* __restrict__ mixhws_b, const float* __restrict__ mixhws2_k,
    const float* __restrict__ mixhws2_b, const float* __restrict__ linHW,
    const float* __restrict__ linHb, const float* __restrict__ linWW,
    const float* __restrict__ linWb, float* __restrict__ g_h,
    float* __restrict__ g_hw, float* __restrict__ g_c) {
  const int b = blockIdx.x, t = threadIdx.x;
  __shared__ float hv[7], wv[7];
  __shared__ float tc[770];
  if (t < 7) { hv[t] = h2v[b * 7 + t]; wv[t] = w2v[b * 7 + t]; }
  if (t == 7) { tc[0] = 0.f; tc[769] = 0.f; }
  __syncthreads();

  if (t < 7) {
    const float cw = convH_w[0], cbv = convH_b[0];
    const float k0 = convH2_k[0], k1 = convH2_k[1], k2 = convH2_k[2], b2 = convH2_b[0];
    const float um = t > 0 ? sigm(hv[t - 1] * cw + cbv) : 0.f;
    const float u0 = sigm(hv[t] * cw + cbv);
    const float up = t < 6 ? sigm(hv[t + 1] * cw + cbv) : 0.f;
    g_h[b * 7 + t] = sigm(k0 * um + k1 * u0 + k2 * up + b2);

    const float a0 = mixhw_k[0], a1 = mixhw_k[1], ab = mixhw_b[0];
    const float q0 = mixhw2_k[0], q1 = mixhw2_k[1], q2 = mixhw2_k[2], qb = mixhw2_b[0];
    const float vm = t > 0 ? sigm(a0 * hv[t - 1] + a1 * wv[t - 1] + ab) : 0.f;
    const float v0 = sigm(a0 * hv[t] + a1 * wv[t] + ab);
    const float vp = t < 6 ? sigm(a0 * hv[t + 1] + a1 * wv[t + 1] + ab) : 0.f;
    g_hw[b * 7 + t] = sigm(q0 * vm + q1 * v0 + q2 * vp + qb);
  }

  const float m0 = mixhws_k[0], m1 = mixhws_k[1], m2 = mixhws_k[2], mb = mixhws_b[0];
#pragma unroll
  for (int j = 0; j < 3; ++j) {
    const int c = t + j * 256;
    float h2l = linHb[c], w2l = linWb[c];
#pragma unroll
    for (int i = 0; i < 7; ++i) {
      h2l += hv[i] * linHW[c * 7 + i];
      w2l += wv[i] * linWW[c * 7 + i];
    }
    tc[1 + c] = sigm(m0 * h2l + m1 * w2l + m2 * s1v[b * 768 + c] + mb);
  }
  __syncthreads();
  const float r0 = mixhws2_k[0], r1 = mixhws2_k[1], r2 = mixhws2_k[2], rb2 = mixhws2_b[0];
#pragma unroll
  for (int j = 0; j < 3; ++j) {
    const int c = t + j * 256;
    g_c[b * 768 + c] = sigm(r0 * tc[c] + r1 * tc[c + 1] + r2 * tc[c + 2] + rb2);
  }
}

// ---------------- apply gates in place on hws ----------------
__global__ __launch_bounds__(256) void k_gapply(__bf16* __restrict__ hws,
                                                const float* __restrict__ g_h,
                                                const float* __restrict__ g_hw,
                                                const float* __restrict__ g_c) {
  const int idx = blockIdx.x * 256 + threadIdx.x;  // chunk of 8 bf16; 25088*288 total
  const int k8 = idx % 288;
  const int p = idx / 288;
  const int b = p / 49, pp = p % 49;
  bf16x8* ptr = (bf16x8*)hws + idx;
  bf16x8 v = *ptr;
  if (k8 < 96) {
    const float g = g_h[b * 7 + pp / 7];
#pragma unroll
    for (int e = 0; e < 8; ++e) v[e] = (__bf16)((float)v[e] * g);
  } else if (k8 < 192) {
    const float g = g_hw[b * 7 + pp % 7];
#pragma unroll
    for (int e = 0; e < 8; ++e) v[e] = (__bf16)((float)v[e] * g);
  } else {
    const float* gcp = g_c + b * 768 + (k8 - 192) * 8;
#pragma unroll
    for (int e = 0; e < 8; ++e) v[e] = (__bf16)((float)v[e] * gcp[e]);
  }
  *ptr = v;
}

// ---------------- launch ----------------
extern "C" void kernel_launch(void* const* d_in, const int* in_sizes, int n_in,
                              void* d_out, int out_size, void* d_ws, size_t ws_size,
                              hipStream_t stream) {
  const float* x        = (const float*)d_in[0];
  const float* Wh       = (const float*)d_in[1];
  const float* bh       = (const float*)d_in[2];
  const float* Ww       = (const float*)d_in[3];
  const float* bw       = (const float*)d_in[4];
  const float* Ws       = (const float*)d_in[5];
  const float* bs       = (const float*)d_in[6];
  const float* convH_w  = (const float*)d_in[7];
  const float* convH_b  = (const float*)d_in[8];
  const float* convH2_k = (const float*)d_in[9];
  const float* convH2_b = (const float*)d_in[10];
  const float* mixhw_k  = (const float*)d_in[11];
  const float* mixhw_b  = (const float*)d_in[12];
  const float* mixhw2_k = (const float*)d_in[13];
  const float* mixhw2_b = (const float*)d_in[14];
  const float* mixhws_k = (const float*)d_in[15];
  const float* mixhws_b = (const float*)d_in[16];
  const float* mixhws2_k= (const float*)d_in[17];
  const float* mixhws2_b= (const float*)d_in[18];
  const float* linHW    = (const float*)d_in[19];
  const float* linHb    = (const float*)d_in[20];
  const float* linWW    = (const float*)d_in[21];
  const float* linWb    = (const float*)d_in[22];
  const float* mixallW  = (const float*)d_in[23];
  const float* mixallb  = (const float*)d_in[24];
  const float* projW    = (const float*)d_in[25];
  const float* projb    = (const float*)d_in[26];
  const float* gatew    = (const float*)d_in[27];
  float* out = (float*)d_out;
  (void)in_sizes; (void)n_in; (void)out_size; (void)ws_size;

  const int M = 25088;  // 512*7*7
  char* ws = (char*)d_ws;
  size_t off = 0;
  auto carve = [&](size_t bytes) -> void* {
    void* p = ws + off;
    off += (bytes + 255) & ~(size_t)255;
    return p;
  };
  __bf16* xb     = (__bf16*)carve((size_t)M * 768 * 2);
  __bf16* Wcat   = (__bf16*)carve((size_t)2304 * 768 * 2);
  __bf16* mixWb  = (__bf16*)carve((size_t)768 * 2304 * 2);
  __bf16* projWb = (__bf16*)carve((size_t)768 * 768 * 2);
  float*  bcat   = (float*)carve(2304 * 4);
  __bf16* hws    = (__bf16*)carve((size_t)M * 2304 * 2);
  __bf16* mixed  = (__bf16*)carve((size_t)M * 768 * 2);
  float*  h2v    = (float*)carve(512 * 7 * 4);
  float*  w2v    = (float*)carve(512 * 7 * 4);
  float*  s1v    = (float*)carve(512 * 768 * 4);
  float*  gh     = (float*)carve(512 * 7 * 4);
  float*  ghw    = (float*)carve(512 * 7 * 4);
  float*  gc     = (float*)carve(512 * 768 * 4);

  k_convert<<<9408, 256, 0, stream>>>(x, xb, (M * 768) / 8);
  k_convert<<<288, 256, 0, stream>>>(Wh, Wcat, 73728);
  k_convert<<<288, 256, 0, stream>>>(Ww, Wcat + 589824, 73728);
  k_convert<<<288, 256, 0, stream>>>(Ws, Wcat + 1179648, 73728);
  k_convert<<<864, 256, 0, stream>>>(mixallW, mixWb, 221184);
  k_convert<<<288, 256, 0, stream>>>(projW, projWb, 73728);
  k_bcat<<<9, 256, 0, stream>>>(bh, bw, bs, bcat);

  // [h|w|s] = gelu(x @ [Wh|Ww|Ws]^T + bcat)   (M x 2304)
  k_gemm<0><<<196 * 18, 256, 0, stream>>>(xb, Wcat, bcat, hws, nullptr, nullptr,
                                          nullptr, 2304, 768);
  k_pool<<<512, 256, 0, stream>>>(hws, h2v, w2v, s1v);
  k_gates<<<512, 256, 0, stream>>>(h2v, w2v, s1v, convH_w, convH_b, convH2_k,
                                   convH2_b, mixhw_k, mixhw_b, mixhw2_k, mixhw2_b,
                                   mixhws_k, mixhws_b, mixhws2_k, mixhws2_b,
                                   linHW, linHb, linWW, linWb, gh, ghw, gc);
  k_gapply<<<28224, 256, 0, stream>>>(hws, gh, ghw, gc);
  // mixed = cat @ mixall_W^T + mixall_b   (M x 768, K=2304)
  k_gemm<1><<<196 * 6, 256, 0, stream>>>(hws, mixWb, mixallb, mixed, nullptr,
                                         nullptr, nullptr, 768, 2304);
  // out = g0*(mixed @ proj_W^T + proj_b) + g1*x   (M x 768, K=768, fp32 out)
  k_gemm<2><<<196 * 6, 256, 0, stream>>>(mixed, projWb, projb, nullptr, out, x,
                                         gatew, 768, 768);
}

// Round 2
// 447.566 us; speedup vs baseline: 1.1193x; 1.1193x over previous
//
#include <hip/hip_runtime.h>
#include <cstdint>
#include <cstddef>

typedef __attribute__((ext_vector_type(8))) __bf16 bf16x8;
typedef __attribute__((ext_vector_type(4))) float f32x4;

__device__ __forceinline__ float sigm(float v) { return 1.0f / (1.0f + expf(-v)); }

// tanh-approx gelu: 0.5v(1+tanh(.79788456(v+.044715v^3))) = v*sigmoid(1.59576912(v+.044715v^3))
__device__ __forceinline__ float gelu_fast(float v) {
  float u = v * (1.0f + 0.044715f * v * v);
  float z = 1.5957691216057308f * u;
  return v / (1.0f + __expf(-z));
}

__device__ __forceinline__ void async16(__bf16* lds, const __bf16* g) {
  __builtin_amdgcn_global_load_lds(
      (const __attribute__((address_space(1))) void*)g,
      (__attribute__((address_space(3))) void*)lds, 16, 0, 0);
}

// ---------------- convert fp32 -> bf16, 8 elems/thread ----------------
__global__ __launch_bounds__(256) void k_convert(const float* __restrict__ src,
                                                 __bf16* __restrict__ dst, int n8) {
  int i = blockIdx.x * 256 + threadIdx.x;
  if (i >= n8) return;
  const f32x4* s4 = (const f32x4*)src;
  f32x4 a = s4[2 * i], b = s4[2 * i + 1];
  bf16x8 o;
#pragma unroll
  for (int e = 0; e < 4; ++e) { o[e] = (__bf16)a[e]; o[4 + e] = (__bf16)b[e]; }
  ((bf16x8*)dst)[i] = o;
}

__global__ __launch_bounds__(256) void k_bcat(const float* __restrict__ bh,
                                              const float* __restrict__ bw,
                                              const float* __restrict__ bs,
                                              float* __restrict__ bcat) {
  int i = blockIdx.x * 256 + threadIdx.x;
  if (i >= 2304) return;
  bcat[i] = i < 768 ? bh[i] : (i < 1536 ? bw[i - 768] : bs[i - 1536]);
}

// transpose + convert: src (R x C) fp32 -> dst (C x R) bf16
__global__ __launch_bounds__(256) void k_transpose_cvt(const float* __restrict__ src,
                                                       __bf16* __restrict__ dst,
                                                       int R, int C) {
  __shared__ float t[32][33];
  const int c0 = blockIdx.x * 32, r0 = blockIdx.y * 32;
  const int tx = threadIdx.x, ty = threadIdx.y;  // 32 x 8
#pragma unroll
  for (int i = 0; i < 32; i += 8)
    if (r0 + ty + i < R && c0 + tx < C) t[ty + i][tx] = src[(size_t)(r0 + ty + i) * C + c0 + tx];
  __syncthreads();
#pragma unroll
  for (int i = 0; i < 32; i += 8)
    if (c0 + ty + i < C && r0 + tx < R)
      dst[(size_t)(c0 + ty + i) * R + r0 + tx] = (__bf16)t[tx][ty + i];
}

// b2 = proj_b + P . mixall_b
__global__ __launch_bounds__(256) void k_b2(const float* __restrict__ P,
                                            const float* __restrict__ bm,
                                            const float* __restrict__ pb,
                                            float* __restrict__ b2) {
  const int d = blockIdx.x * 256 + threadIdx.x;
  if (d >= 768) return;
  float acc = pb[d];
  const float* row = P + (size_t)d * 768;
#pragma unroll 4
  for (int c = 0; c < 768; c += 4) {
    f32x4 p4 = *(const f32x4*)(row + c);
    f32x4 b4 = *(const f32x4*)(bm + c);
    acc += p4[0] * b4[0] + p4[1] * b4[1] + p4[2] * b4[2] + p4[3] * b4[3];
  }
  b2[d] = acc;
}

// ---------------- GEMM, BT layout (A: MxK K-contig, B: NxK K-contig) ----------------
// 128x128 tile, BK=32, 4 waves (2x2), 4x4 mfma_f32_16x16x32_bf16 per wave.
// Double-buffered LDS; stage(t+1) issued BEFORE compute(t); one __syncthreads per K-step
// (its vmcnt(0)+lgkmcnt(0) drain lands after compute hides the load latency). [T3-minimum]
// EPI 0: out_bf16 = gelu(acc + bias[col])
// EPI 2: out_f32  = g0*(acc + bias[col]) + g1*x
// EPI 3: out_bf16 = acc                      (no bias; used for W2 = P.D)
template <int EPI>
__global__ __launch_bounds__(256) void k_gemm(
    const __bf16* __restrict__ A, const __bf16* __restrict__ B,
    const float* __restrict__ bias, __bf16* __restrict__ outB,
    float* __restrict__ outF, const float* __restrict__ xres,
    const float* __restrict__ gatew, int N, int K) {
  __shared__ __bf16 lds[16384];  // A0 | A1 | B0 | B1, each 128x32
  const int tid = threadIdx.x;
  const int wave = tid >> 6, lane = tid & 63;
  const int nTn = N >> 7;
  const int tm = blockIdx.x / nTn, tn = blockIdx.x % nTn;
  const __bf16* Ag = A + (size_t)tm * 128 * K;
  const __bf16* Bg = B + (size_t)tn * 128 * K;
  const size_t sOff = (size_t)(tid >> 2) * K + ((tid & 3) << 3);

  auto stage = [&](int buf, int t) {
    const int k0 = t << 5;
    __bf16* la = lds + buf * 4096;
    __bf16* lb = lds + 8192 + buf * 4096;
    async16(la + wave * 512,        Ag + sOff + k0);
    async16(la + 2048 + wave * 512, Ag + sOff + (size_t)64 * K + k0);
    async16(lb + wave * 512,        Bg + sOff + k0);
    async16(lb + 2048 + wave * 512, Bg + sOff + (size_t)64 * K + k0);
  };

  f32x4 acc[4][4];
#pragma unroll
  for (int m = 0; m < 4; ++m)
#pragma unroll
    for (int n = 0; n < 4; ++n) acc[m][n] = f32x4{0.f, 0.f, 0.f, 0.f};

  const int wr = wave >> 1, wc = wave & 1;
  const int rb = wr * 64 + (lane & 15);
  const int cb = wc * 64 + (lane & 15);
  const int kf = (lane >> 4) << 3;
  const int nt = K >> 5;

  stage(0, 0);
  __syncthreads();
  int cur = 0;
  for (int t = 0; t < nt; ++t) {
    if (t + 1 < nt) stage(cur ^ 1, t + 1);  // prefetch overlaps with compute below
    const __bf16* la = lds + cur * 4096;
    const __bf16* lb = lds + 8192 + cur * 4096;
    bf16x8 af[4], bfv[4];
#pragma unroll
    for (int m = 0; m < 4; ++m) af[m] = *(const bf16x8*)&la[(rb + m * 16) * 32 + kf];
#pragma unroll
    for (int n = 0; n < 4; ++n) bfv[n] = *(const bf16x8*)&lb[(cb + n * 16) * 32 + kf];
#pragma unroll
    for (int m = 0; m < 4; ++m)
#pragma unroll
      for (int n = 0; n < 4; ++n)
        acc[m][n] = __builtin_amdgcn_mfma_f32_16x16x32_bf16(af[m], bfv[n], acc[m][n], 0, 0, 0);
    if (t + 1 < nt) __syncthreads();  // drains vmcnt(0): next buffer staged + reads retired
    cur ^= 1;
  }

  // epilogue: C/D layout col=lane&15, row=(lane>>4)*4+reg  [learn_hip m89]
  const int orow = (lane >> 4) * 4;
  const int ocol = lane & 15;
  float g0 = 0.f, g1 = 0.f;
  if constexpr (EPI == 2) { g0 = gatew[0]; g1 = gatew[1]; }
#pragma unroll
  for (int m = 0; m < 4; ++m) {
#pragma unroll
    for (int n = 0; n < 4; ++n) {
#pragma unroll
      for (int r = 0; r < 4; ++r) {
        const int rg = tm * 128 + wr * 64 + m * 16 + orow + r;
        const int cg = tn * 128 + wc * 64 + n * 16 + ocol;
        if constexpr (EPI == 0) {
          float v = acc[m][n][r] + bias[cg];
          outB[(size_t)rg * N + cg] = (__bf16)gelu_fast(v);
        } else if constexpr (EPI == 2) {
          float v = acc[m][n][r] + bias[cg];
          outF[(size_t)rg * N + cg] = g0 * v + g1 * xres[(size_t)rg * N + cg];
        } else {
          outB[(size_t)rg * N + cg] = (__bf16)acc[m][n][r];
        }
      }
    }
  }
}

// ---------------- pooling: h2v (B,7), w2v (B,7), s1v (B,768) ----------------
__global__ __launch_bounds__(256) void k_pool(const __bf16* __restrict__ hws,
                                              float* __restrict__ h2v,
                                              float* __restrict__ w2v,
                                              float* __restrict__ s1v) {
  const int b = blockIdx.x, t = threadIdx.x;
  const int lane = t & 63, wave = t >> 6;
  const size_t base = (size_t)b * 49 * 2304;
  float hloc[7], wloc[7];
#pragma unroll
  for (int i = 0; i < 7; ++i) { hloc[i] = 0.f; wloc[i] = 0.f; }
  float sacc[8], sacc2[8];
#pragma unroll
  for (int e = 0; e < 8; ++e) { sacc[e] = 0.f; sacc2[e] = 0.f; }

  const bool isH = t < 96, isW = (t >= 96 && t < 192);
  const int off1 = isH ? t * 8 : (isW ? 768 + (t - 96) * 8 : 1536 + (t - 192) * 8);
  const int off2 = 1536 + (64 + t) * 8;

#pragma unroll
  for (int p = 0; p < 49; ++p) {
    const int hi = p / 7, wi = p % 7;
    const __bf16* row = hws + base + (size_t)p * 2304;
    bf16x8 v = *(const bf16x8*)(row + off1);
    float s8 = 0.f;
#pragma unroll
    for (int e = 0; e < 8; ++e) s8 += (float)v[e];
    if (isH) hloc[hi] += s8;
    else if (isW) wloc[wi] += s8;
    else {
#pragma unroll
      for (int e = 0; e < 8; ++e) sacc[e] += (float)v[e];
    }
    if (t < 32) {
      bf16x8 v2 = *(const bf16x8*)(row + off2);
#pragma unroll
      for (int e = 0; e < 8; ++e) sacc2[e] += (float)v2[e];
    }
  }

  if (t >= 192) {
#pragma unroll
    for (int e = 0; e < 8; ++e)
      s1v[b * 768 + (t - 192) * 8 + e] = sacc[e] * (1.f / 49.f);
  }
  if (t < 32) {
#pragma unroll
    for (int e = 0; e < 8; ++e)
      s1v[b * 768 + 512 + t * 8 + e] = sacc2[e] * (1.f / 49.f);
  }

  __shared__ float red[4][14];
#pragma unroll
  for (int i = 0; i < 7; ++i) {
    float hv = hloc[i], wv = wloc[i];
#pragma unroll
    for (int s = 32; s; s >>= 1) { hv += __shfl_xor(hv, s); wv += __shfl_xor(wv, s); }
    if (lane == 0) { red[wave][i] = hv; red[wave][7 + i] = wv; }
  }
  __syncthreads();
  if (t < 7) {
    h2v[b * 7 + t] = (red[0][t] + red[1][t] + red[2][t] + red[3][t]) * (1.f / 5376.f);
  } else if (t >= 16 && t < 23) {
    const int i = t - 16;
    w2v[b * 7 + i] =
        (red[0][7 + i] + red[1][7 + i] + red[2][7 + i] + red[3][7 + i]) * (1.f / 5376.f);
  }
}

// ---------------- gates: g_h (B,7), g_hw (B,7), g_c (B,768) ----------------
__global__ __launch_bounds__(256) void k_gates(
    const float* __restrict__ h2v, const float* __restrict__ w2v,
    const float* __restrict__ s1v, const float* __restrict__ convH_w,
    const float* __restrict__ convH_b, const float* __restrict__ convH2_k,
    const float* __restrict__ convH2_b, const float* __restrict__ mixhw_k,
    const float* __restrict__ mixhw_b, const float* __restrict__ mixhw2_k,
    const float* __restrict__ mixhw2_b, const float* __restrict__ mixhws_k,
    const float* __restrict__ mixhws_b, const float* __restrict__ mixhws2_k,
    const float* __restrict__ mixhws2_b, const float* __restrict__ linHW,
    const float* __restrict__ linHb, const float* __restrict__ linWW,
    const float* __restrict__ linWb, float* __restrict__ g_h,
    float* __restrict__ g_hw, float* __restrict__ g_c) {
  const int b = blockIdx.x, t = threadIdx.x;
  __shared__ float hv[7], wv[7];
  __shared__ float tc[770];
  if (t < 7) { hv[t] = h2v[b * 7 + t]; wv[t] = w2v[b * 7 + t]; }
  if (t == 7) { tc[0] = 0.f; tc[769] = 0.f; }
  __syncthreads();

  if (t < 7) {
    const float cw = convH_w[0], cbv = convH_b[0];
    const float k0 = convH2_k[0], k1 = convH2_k[1], k2 = convH2_k[2], b2 = convH2_b[0];
    const float um = t > 0 ? sigm(hv[t - 1] * cw + cbv) : 0.f;
    const float u0 = sigm(hv[t] * cw + cbv);
    const float up = t < 6 ? sigm(hv[t + 1] * cw + cbv) : 0.f;
    g_h[b * 7 + t] = sigm(k0 * um + k1 * u0 + k2 * up + b2);

    const float a0 = mixhw_k[0], a1 = mixhw_k[1], ab = mixhw_b[0];
    const float q0 = mixhw2_k[0], q1 = mixhw2_k[1], q2 = mixhw2_k[2], qb = mixhw2_b[0];
    const float vm = t > 0 ? sigm(a0 * hv[t - 1] + a1 * wv[t - 1] + ab) : 0.f;
    const float v0 = sigm(a0 * hv[t] + a1 * wv[t] + ab);
    const float vp = t < 6 ? sigm(a0 * hv[t + 1] + a1 * wv[t + 1] + ab) : 0.f;
    g_hw[b * 7 + t] = sigm(q0 * vm + q1 * v0 + q2 * vp + qb);
  }

  const float m0 = mixhws_k[0], m1 = mixhws_k[1], m2 = mixhws_k[2], mb = mixhws_b[0];
#pragma unroll
  for (int j = 0; j < 3; ++j) {
    const int c = t + j * 256;
    float h2l = linHb[c], w2l = linWb[c];
#pragma unroll
    for (int i = 0; i < 7; ++i) {
      h2l += hv[i] * linHW[c * 7 + i];
      w2l += wv[i] * linWW[c * 7 + i];
    }
    tc[1 + c] = sigm(m0 * h2l + m1 * w2l + m2 * s1v[b * 768 + c] + mb);
  }
  __syncthreads();
  const float r0 = mixhws2_k[0], r1 = mixhws2_k[1], r2 = mixhws2_k[2], rb2 = mixhws2_b[0];
#pragma unroll
  for (int j = 0; j < 3; ++j) {
    const int c = t + j * 256;
    g_c[b * 768 + c] = sigm(r0 * tc[c] + r1 * tc[c + 1] + r2 * tc[c + 2] + rb2);
  }
}

// ---------------- apply gates in place on hws ----------------
__global__ __launch_bounds__(256) void k_gapply(__bf16* __restrict__ hws,
                                                const float* __restrict__ g_h,
                                                const float* __restrict__ g_hw,
                                                const float* __restrict__ g_c) {
  const int idx = blockIdx.x * 256 + threadIdx.x;  // chunk of 8 bf16
  const int k8 = idx % 288;
  const int p = idx / 288;
  const int b = p / 49, pp = p % 49;
  bf16x8* ptr = (bf16x8*)hws + idx;
  bf16x8 v = *ptr;
  if (k8 < 96) {
    const float g = g_h[b * 7 + pp / 7];
#pragma unroll
    for (int e = 0; e < 8; ++e) v[e] = (__bf16)((float)v[e] * g);
  } else if (k8 < 192) {
    const float g = g_hw[b * 7 + pp % 7];
#pragma unroll
    for (int e = 0; e < 8; ++e) v[e] = (__bf16)((float)v[e] * g);
  } else {
    const float* gcp = g_c + b * 768 + (k8 - 192) * 8;
#pragma unroll
    for (int e = 0; e < 8; ++e) v[e] = (__bf16)((float)v[e] * gcp[e]);
  }
  *ptr = v;
}

// ---------------- launch ----------------
extern "C" void kernel_launch(void* const* d_in, const int* in_sizes, int n_in,
                              void* d_out, int out_size, void* d_ws, size_t ws_size,
                              hipStream_t stream) {
  const float* x        = (const float*)d_in[0];
  const float* Wh       = (const float*)d_in[1];
  const float* bh       = (const float*)d_in[2];
  const float* Ww       = (const float*)d_in[3];
  const float* bw       = (const float*)d_in[4];
  const float* Ws       = (const float*)d_in[5];
  const float* bs       = (const float*)d_in[6];
  const float* convH_w  = (const float*)d_in[7];
  const float* convH_b  = (const float*)d_in[8];
  const float* convH2_k = (const float*)d_in[9];
  const float* convH2_b = (const float*)d_in[10];
  const float* mixhw_k  = (const float*)d_in[11];
  const float* mixhw_b  = (const float*)d_in[12];
  const float* mixhw2_k = (const float*)d_in[13];
  const float* mixhw2_b = (const float*)d_in[14];
  const float* mixhws_k = (const float*)d_in[15];
  const float* mixhws_b = (const float*)d_in[16];
  const float* mixhws2_k= (const float*)d_in[17];
  const float* mixhws2_b= (const float*)d_in[18];
  const float* linHW    = (const float*)d_in[19];
  const float* linHb    = (const float*)d_in[20];
  const float* linWW    = (const float*)d_in[21];
  const float* linWb    = (const float*)d_in[22];
  const float* mixallW  = (const float*)d_in[23];
  const float* mixallb  = (const float*)d_in[24];
  const float* projW    = (const float*)d_in[25];
  const float* projb    = (const float*)d_in[26];
  const float* gatew    = (const float*)d_in[27];
  float* out = (float*)d_out;
  (void)in_sizes; (void)n_in; (void)out_size; (void)ws_size;

  const int M = 25088;  // 512*7*7
  char* ws = (char*)d_ws;
  size_t off = 0;
  auto carve = [&](size_t bytes) -> void* {
    void* p = ws + off;
    off += (bytes + 255) & ~(size_t)255;
    return p;
  };
  __bf16* xb     = (__bf16*)carve((size_t)M * 768 * 2);
  __bf16* Wcat   = (__bf16*)carve((size_t)2304 * 768 * 2);
  __bf16* Pb     = (__bf16*)carve((size_t)768 * 768 * 2);
  __bf16* Dt     = (__bf16*)carve((size_t)2304 * 768 * 2);
  __bf16* W2     = (__bf16*)carve((size_t)768 * 2304 * 2);
  float*  bcat   = (float*)carve(2304 * 4);
  float*  b2     = (float*)carve(768 * 4);
  __bf16* hws    = (__bf16*)carve((size_t)M * 2304 * 2);
  float*  h2v    = (float*)carve(512 * 7 * 4);
  float*  w2v    = (float*)carve(512 * 7 * 4);
  float*  s1v    = (float*)carve(512 * 768 * 4);
  float*  gh     = (float*)carve(512 * 7 * 4);
  float*  ghw    = (float*)carve(512 * 7 * 4);
  float*  gc     = (float*)carve(512 * 768 * 4);

  k_convert<<<9408, 256, 0, stream>>>(x, xb, (M * 768) / 8);
  k_convert<<<288, 256, 0, stream>>>(Wh, Wcat, 73728);
  k_convert<<<288, 256, 0, stream>>>(Ww, Wcat + 589824, 73728);
  k_convert<<<288, 256, 0, stream>>>(Ws, Wcat + 1179648, 73728);
  k_convert<<<288, 256, 0, stream>>>(projW, Pb, 73728);
  k_transpose_cvt<<<dim3(72, 24), dim3(32, 8), 0, stream>>>(mixallW, Dt, 768, 2304);
  k_bcat<<<9, 256, 0, stream>>>(bh, bw, bs, bcat);
  k_b2<<<3, 256, 0, stream>>>(projW, mixallb, projb, b2);

  // W2 = P . D : (768 x 2304), A = Pb (768x768 K-contig), B = Dt (2304x768 K-contig)
  k_gemm<3><<<6 * 18, 256, 0, stream>>>(Pb, Dt, nullptr, W2, nullptr, nullptr,
                                        nullptr, 2304, 768);
  // [h|w|s] = gelu(x @ [Wh|Ww|Ws]^T + bcat)   (M x 2304)
  k_gemm<0><<<196 * 18, 256, 0, stream>>>(xb, Wcat, bcat, hws, nullptr, nullptr,
                                          nullptr, 2304, 768);
  k_pool<<<512, 256, 0, stream>>>(hws, h2v, w2v, s1v);
  k_gates<<<512, 256, 0, stream>>>(h2v, w2v, s1v, convH_w, convH_b, convH2_k,
                                   convH2_b, mixhw_k, mixhw_b, mixhw2_k, mixhw2_b,
                                   mixhws_k, mixhws_b, mixhws2_k, mixhws2_b,
                                   linHW, linHb, linWW, linWb, gh, ghw, gc);
  k_gapply<<<28224, 256, 0, stream>>>(hws, gh, ghw, gc);
  // out = g0*(cat @ W2^T + b2) + g1*x   (M x 768, K=2304, fp32 out)
  k_gemm<2><<<196 * 6, 256, 0, stream>>>(hws, W2, b2, nullptr, out, x,
                                         gatew, 768, 2304);
}

// Round 3
// 441.424 us; speedup vs baseline: 1.1349x; 1.0139x over previous
//
#include <hip/hip_runtime.h>
#include <cstdint>
#include <cstddef>

typedef __attribute__((ext_vector_type(8))) __bf16 bf16x8;
typedef __attribute__((ext_vector_type(4))) float f32x4;

__device__ __forceinline__ float sigm(float v) { return 1.0f / (1.0f + expf(-v)); }

__device__ __forceinline__ float gelu_fast(float v) {
  float u = v * (1.0f + 0.044715f * v * v);
  float z = 1.5957691216057308f * u;
  return v / (1.0f + __expf(-z));
}

__device__ __forceinline__ void async16(__bf16* lds, const __bf16* g) {
  __builtin_amdgcn_global_load_lds(
      (const __attribute__((address_space(1))) void*)g,
      (__attribute__((address_space(3))) void*)lds, 16, 0, 0);
}

// ---------------- convert fp32 -> bf16, 8 elems/thread ----------------
__global__ __launch_bounds__(256) void k_convert(const float* __restrict__ src,
                                                 __bf16* __restrict__ dst, int n8) {
  int i = blockIdx.x * 256 + threadIdx.x;
  if (i >= n8) return;
  const f32x4* s4 = (const f32x4*)src;
  f32x4 a = s4[2 * i], b = s4[2 * i + 1];
  bf16x8 o;
#pragma unroll
  for (int e = 0; e < 4; ++e) { o[e] = (__bf16)a[e]; o[4 + e] = (__bf16)b[e]; }
  ((bf16x8*)dst)[i] = o;
}

__global__ __launch_bounds__(256) void k_bcat(const float* __restrict__ bh,
                                              const float* __restrict__ bw,
                                              const float* __restrict__ bs,
                                              float* __restrict__ bcat) {
  int i = blockIdx.x * 256 + threadIdx.x;
  if (i >= 2304) return;
  bcat[i] = i < 768 ? bh[i] : (i < 1536 ? bw[i - 768] : bs[i - 1536]);
}

// transpose + convert: src (R x C) fp32 -> dst (C x R) bf16
__global__ __launch_bounds__(256) void k_transpose_cvt(const float* __restrict__ src,
                                                       __bf16* __restrict__ dst,
                                                       int R, int C) {
  __shared__ float t[32][33];
  const int c0 = blockIdx.x * 32, r0 = blockIdx.y * 32;
  const int tx = threadIdx.x, ty = threadIdx.y;  // 32 x 8
#pragma unroll
  for (int i = 0; i < 32; i += 8)
    if (r0 + ty + i < R && c0 + tx < C) t[ty + i][tx] = src[(size_t)(r0 + ty + i) * C + c0 + tx];
  __syncthreads();
#pragma unroll
  for (int i = 0; i < 32; i += 8)
    if (c0 + ty + i < C && r0 + tx < R)
      dst[(size_t)(c0 + ty + i) * R + r0 + tx] = (__bf16)t[tx][ty + i];
}

// b2 = proj_b + P . mixall_b
__global__ __launch_bounds__(256) void k_b2(const float* __restrict__ P,
                                            const float* __restrict__ bm,
                                            const float* __restrict__ pb,
                                            float* __restrict__ b2) {
  const int d = blockIdx.x * 256 + threadIdx.x;
  if (d >= 768) return;
  float acc = pb[d];
  const float* row = P + (size_t)d * 768;
#pragma unroll 4
  for (int c = 0; c < 768; c += 4) {
    f32x4 p4 = *(const f32x4*)(row + c);
    f32x4 b4 = *(const f32x4*)(bm + c);
    acc += p4[0] * b4[0] + p4[1] * b4[1] + p4[2] * b4[2] + p4[3] * b4[3];
  }
  b2[d] = acc;
}

// ============ 256x256 8-phase GEMM (BT layout), BK=64, 8 waves ============
// A: MxK K-contig, B: NxK K-contig. M%256==0, N%256==0, K%128==0.
// LDS 128 KiB: A0|A1|B0|B1 tiles of 256x64 bf16, row 128B, XOR-swizzled
// (byte ^= (row&7)<<4) on both staging-source and ds_read (rule #21).
// Phases per iter (tiles T0=2i in buf0, T1=2i+1 in buf1); per phase:
// {ds_reads, 1 half-tile stage, s_barrier, lgkmcnt(0), setprio(1)+16 MFMA,
//  [vmcnt(4) at p3/p7], s_barrier}.
template <int EPI>
__global__ __launch_bounds__(512, 1) void k_gemm256(
    const __bf16* __restrict__ A, const __bf16* __restrict__ B,
    const float* __restrict__ bias, __bf16* __restrict__ outB,
    float* __restrict__ outF, const float* __restrict__ xres,
    const float* __restrict__ gatew, int N, int K) {
  __shared__ __bf16 lds[65536];  // 128 KiB
  const int tid = threadIdx.x;
  const int lane = tid & 63, wid = tid >> 6;
  const int wr = wid >> 2, wc = wid & 3;  // wave grid 2 x 4

  // bijective XCD swizzle (m204) + tn-inner for A-panel L2 reuse
  const int nwg = gridDim.x;
  const int q = nwg >> 3, r = nwg & 7;
  const int xcd = blockIdx.x & 7, idx = blockIdx.x >> 3;
  const int wgid = (xcd < r ? xcd * (q + 1) : r * (q + 1) + (xcd - r) * q) + idx;
  const int nTn = N >> 8;
  const int tm = wgid / nTn, tn = wgid % nTn;

  const __bf16* Ag = A + (size_t)tm * 256 * K;
  const __bf16* Bg = B + (size_t)tn * 256 * K;

  // stage one half-tile (128 rows x 64 k) of operand Og into lds[base + h*8192 ...]
  // linear LDS dest; global source col pre-XOR'd so that a swizzled read inverts it.
  auto stageH = [&](const __bf16* Og, int base, int kt, int h) {
#pragma unroll
    for (int j = 0; j < 2; ++j) {
      const int lin = j * 512 + tid;
      const int row = h * 128 + (lin >> 3);
      const int sc = ((lin & 7) << 3) ^ ((row & 7) << 3);  // element offset in row
      async16(&lds[base + h * 8192 + lin * 8],
              Og + (size_t)row * K + kt * 64 + sc);
    }
  };

  f32x4 acc[8][4];
#pragma unroll
  for (int m = 0; m < 8; ++m)
#pragma unroll
    for (int n = 0; n < 4; ++n) acc[m][n] = f32x4{0.f, 0.f, 0.f, 0.f};

  bf16x8 a[4][2], b[4][2];
  const int g8 = (lane >> 4) << 3;
  const int rowA0 = wr * 128 + (lane & 15);
  const int rowB0 = wc * 64 + (lane & 15);

  auto ldA = [&](int base, int mh) {
#pragma unroll
    for (int mm = 0; mm < 4; ++mm) {
      const int row = rowA0 + (mh * 4 + mm) * 16;
      const int sw = (row & 7) << 3;
      const __bf16* p = &lds[base + row * 64];
      a[mm][0] = *(const bf16x8*)&p[g8 ^ sw];
      a[mm][1] = *(const bf16x8*)&p[(32 + g8) ^ sw];
    }
  };
  auto ldB2 = [&](int base, int nh) {
#pragma unroll
    for (int nn = 0; nn < 2; ++nn) {
      const int n = nh * 2 + nn;
      const int row = rowB0 + n * 16;
      const int sw = (row & 7) << 3;
      const __bf16* p = &lds[base + row * 64];
      b[n][0] = *(const bf16x8*)&p[g8 ^ sw];
      b[n][1] = *(const bf16x8*)&p[(32 + g8) ^ sw];
    }
  };
  auto mma = [&](int mh, int nh) {
    __builtin_amdgcn_s_setprio(1);
#pragma unroll
    for (int mm = 0; mm < 4; ++mm)
#pragma unroll
      for (int nn = 0; nn < 2; ++nn) {
        const int n = nh * 2 + nn, m = mh * 4 + mm;
        acc[m][n] = __builtin_amdgcn_mfma_f32_16x16x32_bf16(a[mm][0], b[n][0], acc[m][n], 0, 0, 0);
        acc[m][n] = __builtin_amdgcn_mfma_f32_16x16x32_bf16(a[mm][1], b[n][1], acc[m][n], 0, 0, 0);
      }
    __builtin_amdgcn_s_setprio(0);
  };

  const int NT = K >> 6, NI = NT >> 1;
  // LDS element bases: A0=0, A1=16384, B0=32768, B1=49152

  // prologue: B(T0), A(T0), B(T1)  (12 loads/wave); T0 ready after vmcnt(4)
  stageH(Bg, 32768, 0, 0); stageH(Bg, 32768, 0, 1);
  stageH(Ag, 0,     0, 0); stageH(Ag, 0,     0, 1);
  stageH(Bg, 49152, 1, 0); stageH(Bg, 49152, 1, 1);
  asm volatile("s_waitcnt vmcnt(4)" ::: "memory");
  __builtin_amdgcn_s_barrier();

  for (int i = 0; i < NI; ++i) {
    const int T1 = 2 * i + 1;
    const bool st = (i + 1) < NI;
    // p0: read A0(m0-3)+B0(n0-1); stage A(T1).h0 -> A1
    ldA(0, 0); ldB2(32768, 0);
    stageH(Ag, 16384, T1, 0);
    __builtin_amdgcn_s_barrier();
    asm volatile("s_waitcnt lgkmcnt(0)" ::: "memory");
    mma(0, 0);
    __builtin_amdgcn_s_barrier();
    // p1: read B0(n2-3); stage A(T1).h1
    ldB2(32768, 1);
    stageH(Ag, 16384, T1, 1);
    __builtin_amdgcn_s_barrier();
    asm volatile("s_waitcnt lgkmcnt(0)" ::: "memory");
    mma(0, 1);
    __builtin_amdgcn_s_barrier();
    // p2: read A0(m4-7); stage B(T0+2).h0 -> B0
    ldA(0, 1);
    if (st) stageH(Bg, 32768, T1 + 1, 0);
    __builtin_amdgcn_s_barrier();
    asm volatile("s_waitcnt lgkmcnt(0)" ::: "memory");
    mma(1, 0);
    __builtin_amdgcn_s_barrier();
    // p3: stage B(T0+2).h1; vmcnt covers T1 for p4 reads
    if (st) stageH(Bg, 32768, T1 + 1, 1);
    __builtin_amdgcn_s_barrier();
    mma(1, 1);
    if (st) { asm volatile("s_waitcnt vmcnt(4)" ::: "memory"); }
    else    { asm volatile("s_waitcnt vmcnt(0)" ::: "memory"); }
    __builtin_amdgcn_s_barrier();
    // p4: read A1(m0-3)+B1(n0-1); stage A(T0+2).h0 -> A0
    ldA(16384, 0); ldB2(49152, 0);
    if (st) stageH(Ag, 0, T1 + 1, 0);
    __builtin_amdgcn_s_barrier();
    asm volatile("s_waitcnt lgkmcnt(0)" ::: "memory");
    mma(0, 0);
    __builtin_amdgcn_s_barrier();
    // p5: read B1(n2-3); stage A(T0+2).h1
    ldB2(49152, 1);
    if (st) stageH(Ag, 0, T1 + 1, 1);
    __builtin_amdgcn_s_barrier();
    asm volatile("s_waitcnt lgkmcnt(0)" ::: "memory");
    mma(0, 1);
    __builtin_amdgcn_s_barrier();
    // p6: read A1(m4-7); stage B(T1+2).h0 -> B1
    ldA(16384, 1);
    if (st) stageH(Bg, 49152, T1 + 2, 0);
    __builtin_amdgcn_s_barrier();
    asm volatile("s_waitcnt lgkmcnt(0)" ::: "memory");
    mma(1, 0);
    __builtin_amdgcn_s_barrier();
    // p7: stage B(T1+2).h1; vmcnt covers T0+2 for next-iter p0 reads
    if (st) stageH(Bg, 49152, T1 + 2, 1);
    __builtin_amdgcn_s_barrier();
    mma(1, 1);
    if (st) { asm volatile("s_waitcnt vmcnt(4)" ::: "memory"); }
    __builtin_amdgcn_s_barrier();
  }

  // epilogue: C/D layout col=lane&15, row=(lane>>4)*4+reg  [m89]
  const int orow = (lane >> 4) * 4;
  const int ocol = lane & 15;
  float g0 = 0.f, g1 = 0.f;
  if constexpr (EPI == 2) { g0 = gatew[0]; g1 = gatew[1]; }
#pragma unroll
  for (int m = 0; m < 8; ++m) {
#pragma unroll
    for (int n = 0; n < 4; ++n) {
#pragma unroll
      for (int rr = 0; rr < 4; ++rr) {
        const int rg = tm * 256 + wr * 128 + m * 16 + orow + rr;
        const int cg = tn * 256 + wc * 64 + n * 16 + ocol;
        if constexpr (EPI == 0) {
          float v = acc[m][n][rr] + bias[cg];
          outB[(size_t)rg * N + cg] = (__bf16)gelu_fast(v);
        } else if constexpr (EPI == 2) {
          float v = acc[m][n][rr] + bias[cg];
          outF[(size_t)rg * N + cg] = g0 * v + g1 * xres[(size_t)rg * N + cg];
        } else {
          outB[(size_t)rg * N + cg] = (__bf16)acc[m][n][rr];
        }
      }
    }
  }
}

// ---------------- pooling: h2v (B,7), w2v (B,7), s1v (B,768) ----------------
__global__ __launch_bounds__(256) void k_pool(const __bf16* __restrict__ hws,
                                              float* __restrict__ h2v,
                                              float* __restrict__ w2v,
                                              float* __restrict__ s1v) {
  const int b = blockIdx.x, t = threadIdx.x;
  const int lane = t & 63, wave = t >> 6;
  const size_t base = (size_t)b * 49 * 2304;
  float hloc[7], wloc[7];
#pragma unroll
  for (int i = 0; i < 7; ++i) { hloc[i] = 0.f; wloc[i] = 0.f; }
  float sacc[8], sacc2[8];
#pragma unroll
  for (int e = 0; e < 8; ++e) { sacc[e] = 0.f; sacc2[e] = 0.f; }

  const bool isH = t < 96, isW = (t >= 96 && t < 192);
  const int off1 = isH ? t * 8 : (isW ? 768 + (t - 96) * 8 : 1536 + (t - 192) * 8);
  const int off2 = 1536 + (64 + t) * 8;

#pragma unroll
  for (int p = 0; p < 49; ++p) {
    const int hi = p / 7, wi = p % 7;
    const __bf16* row = hws + base + (size_t)p * 2304;
    bf16x8 v = *(const bf16x8*)(row + off1);
    float s8 = 0.f;
#pragma unroll
    for (int e = 0; e < 8; ++e) s8 += (float)v[e];
    if (isH) hloc[hi] += s8;
    else if (isW) wloc[wi] += s8;
    else {
#pragma unroll
      for (int e = 0; e < 8; ++e) sacc[e] += (float)v[e];
    }
    if (t < 32) {
      bf16x8 v2 = *(const bf16x8*)(row + off2);
#pragma unroll
      for (int e = 0; e < 8; ++e) sacc2[e] += (float)v2[e];
    }
  }

  if (t >= 192) {
#pragma unroll
    for (int e = 0; e < 8; ++e)
      s1v[b * 768 + (t - 192) * 8 + e] = sacc[e] * (1.f / 49.f);
  }
  if (t < 32) {
#pragma unroll
    for (int e = 0; e < 8; ++e)
      s1v[b * 768 + 512 + t * 8 + e] = sacc2[e] * (1.f / 49.f);
  }

  __shared__ float red[4][14];
#pragma unroll
  for (int i = 0; i < 7; ++i) {
    float hv = hloc[i], wv = wloc[i];
#pragma unroll
    for (int s = 32; s; s >>= 1) { hv += __shfl_xor(hv, s); wv += __shfl_xor(wv, s); }
    if (lane == 0) { red[wave][i] = hv; red[wave][7 + i] = wv; }
  }
  __syncthreads();
  if (t < 7) {
    h2v[b * 7 + t] = (red[0][t] + red[1][t] + red[2][t] + red[3][t]) * (1.f / 5376.f);
  } else if (t >= 16 && t < 23) {
    const int i = t - 16;
    w2v[b * 7 + i] =
        (red[0][7 + i] + red[1][7 + i] + red[2][7 + i] + red[3][7 + i]) * (1.f / 5376.f);
  }
}

// ---------------- gates ----------------
__global__ __launch_bounds__(256) void k_gates(
    const float* __restrict__ h2v, const float* __restrict__ w2v,
    const float* __restrict__ s1v, const float* __restrict__ convH_w,
    const float* __restrict__ convH_b, const float* __restrict__ convH2_k,
    const float* __restrict__ convH2_b, const float* __restrict__ mixhw_k,
    const float* __restrict__ mixhw_b, const float* __restrict__ mixhw2_k,
    const float* __restrict__ mixhw2_b, const float* __restrict__ mixhws_k,
    const float* __restrict__ mixhws_b, const float* __restrict__ mixhws2_k,
    const float* __restrict__ mixhws2_b, const float* __restrict__ linHW,
    const float* __restrict__ linHb, const float* __restrict__ linWW,
    const float* __restrict__ linWb, float* __restrict__ g_h,
    float* __restrict__ g_hw, float* __restrict__ g_c) {
  const int b = blockIdx.x, t = threadIdx.x;
  __shared__ float hv[7], wv[7];
  __shared__ float tc[770];
  if (t < 7) { hv[t] = h2v[b * 7 + t]; wv[t] = w2v[b * 7 + t]; }
  if (t == 7) { tc[0] = 0.f; tc[769] = 0.f; }
  __syncthreads();

  if (t < 7) {
    const float cw = convH_w[0], cbv = convH_b[0];
    const float k0 = convH2_k[0], k1 = convH2_k[1], k2 = convH2_k[2], b2 = convH2_b[0];
    const float um = t > 0 ? sigm(hv[t - 1] * cw + cbv) : 0.f;
    const float u0 = sigm(hv[t] * cw + cbv);
    const float up = t < 6 ? sigm(hv[t + 1] * cw + cbv) : 0.f;
    g_h[b * 7 + t] = sigm(k0 * um + k1 * u0 + k2 * up + b2);

    const float a0 = mixhw_k[0], a1 = mixhw_k[1], ab = mixhw_b[0];
    const float q0 = mixhw2_k[0], q1 = mixhw2_k[1], q2 = mixhw2_k[2], qb = mixhw2_b[0];
    const float vm = t > 0 ? sigm(a0 * hv[t - 1] + a1 * wv[t - 1] + ab) : 0.f;
    const float v0 = sigm(a0 * hv[t] + a1 * wv[t] + ab);
    const float vp = t < 6 ? sigm(a0 * hv[t + 1] + a1 * wv[t + 1] + ab) : 0.f;
    g_hw[b * 7 + t] = sigm(q0 * vm + q1 * v0 + q2 * vp + qb);
  }

  const float m0 = mixhws_k[0], m1 = mixhws_k[1], m2 = mixhws_k[2], mb = mixhws_b[0];
#pragma unroll
  for (int j = 0; j < 3; ++j) {
    const int c = t + j * 256;
    float h2l = linHb[c], w2l = linWb[c];
#pragma unroll
    for (int i = 0; i < 7; ++i) {
      h2l += hv[i] * linHW[c * 7 + i];
      w2l += wv[i] * linWW[c * 7 + i];
    }
    tc[1 + c] = sigm(m0 * h2l + m1 * w2l + m2 * s1v[b * 768 + c] + mb);
  }
  __syncthreads();
  const float r0 = mixhws2_k[0], r1 = mixhws2_k[1], r2 = mixhws2_k[2], rb2 = mixhws2_b[0];
#pragma unroll
  for (int j = 0; j < 3; ++j) {
    const int c = t + j * 256;
    g_c[b * 768 + c] = sigm(r0 * tc[c] + r1 * tc[c + 1] + r2 * tc[c + 2] + rb2);
  }
}

// ---------------- apply gates in place on hws ----------------
__global__ __launch_bounds__(256) void k_gapply(__bf16* __restrict__ hws,
                                                const float* __restrict__ g_h,
                                                const float* __restrict__ g_hw,
                                                const float* __restrict__ g_c) {
  const int idx = blockIdx.x * 256 + threadIdx.x;  // chunk of 8 bf16
  const int k8 = idx % 288;
  const int p = idx / 288;
  const int b = p / 49, pp = p % 49;
  bf16x8* ptr = (bf16x8*)hws + idx;
  bf16x8 v = *ptr;
  if (k8 < 96) {
    const float g = g_h[b * 7 + pp / 7];
#pragma unroll
    for (int e = 0; e < 8; ++e) v[e] = (__bf16)((float)v[e] * g);
  } else if (k8 < 192) {
    const float g = g_hw[b * 7 + pp % 7];
#pragma unroll
    for (int e = 0; e < 8; ++e) v[e] = (__bf16)((float)v[e] * g);
  } else {
    const float* gcp = g_c + b * 768 + (k8 - 192) * 8;
#pragma unroll
    for (int e = 0; e < 8; ++e) v[e] = (__bf16)((float)v[e] * gcp[e]);
  }
  *ptr = v;
}

// ---------------- launch ----------------
extern "C" void kernel_launch(void* const* d_in, const int* in_sizes, int n_in,
                              void* d_out, int out_size, void* d_ws, size_t ws_size,
                              hipStream_t stream) {
  const float* x        = (const float*)d_in[0];
  const float* Wh       = (const float*)d_in[1];
  const float* bh       = (const float*)d_in[2];
  const float* Ww       = (const float*)d_in[3];
  const float* bw       = (const float*)d_in[4];
  const float* Ws       = (const float*)d_in[5];
  const float* bs       = (const float*)d_in[6];
  const float* convH_w  = (const float*)d_in[7];
  const float* convH_b  = (const float*)d_in[8];
  const float* convH2_k = (const float*)d_in[9];
  const float* convH2_b = (const float*)d_in[10];
  const float* mixhw_k  = (const float*)d_in[11];
  const float* mixhw_b  = (const float*)d_in[12];
  const float* mixhw2_k = (const float*)d_in[13];
  const float* mixhw2_b = (const float*)d_in[14];
  const float* mixhws_k = (const float*)d_in[15];
  const float* mixhws_b = (const float*)d_in[16];
  const float* mixhws2_k= (const float*)d_in[17];
  const float* mixhws2_b= (const float*)d_in[18];
  const float* linHW    = (const float*)d_in[19];
  const float* linHb    = (const float*)d_in[20];
  const float* linWW    = (const float*)d_in[21];
  const float* linWb    = (const float*)d_in[22];
  const float* mixallW  = (const float*)d_in[23];
  const float* mixallb  = (const float*)d_in[24];
  const float* projW    = (const float*)d_in[25];
  const float* projb    = (const float*)d_in[26];
  const float* gatew    = (const float*)d_in[27];
  float* out = (float*)d_out;
  (void)in_sizes; (void)n_in; (void)out_size; (void)ws_size;

  const int M = 25088;  // 512*7*7
  char* ws = (char*)d_ws;
  size_t off = 0;
  auto carve = [&](size_t bytes) -> void* {
    void* p = ws + off;
    off += (bytes + 255) & ~(size_t)255;
    return p;
  };
  __bf16* xb     = (__bf16*)carve((size_t)M * 768 * 2);
  __bf16* Wcat   = (__bf16*)carve((size_t)2304 * 768 * 2);
  __bf16* Pb     = (__bf16*)carve((size_t)768 * 768 * 2);
  __bf16* Dt     = (__bf16*)carve((size_t)2304 * 768 * 2);
  __bf16* W2     = (__bf16*)carve((size_t)768 * 2304 * 2);
  float*  bcat   = (float*)carve(2304 * 4);
  float*  b2     = (float*)carve(768 * 4);
  __bf16* hws    = (__bf16*)carve((size_t)M * 2304 * 2);
  float*  h2v    = (float*)carve(512 * 7 * 4);
  float*  w2v    = (float*)carve(512 * 7 * 4);
  float*  s1v    = (float*)carve(512 * 768 * 4);
  float*  gh     = (float*)carve(512 * 7 * 4);
  float*  ghw    = (float*)carve(512 * 7 * 4);
  float*  gc     = (float*)carve(512 * 768 * 4);

  k_convert<<<9408, 256, 0, stream>>>(x, xb, (M * 768) / 8);
  k_convert<<<288, 256, 0, stream>>>(Wh, Wcat, 73728);
  k_convert<<<288, 256, 0, stream>>>(Ww, Wcat + 589824, 73728);
  k_convert<<<288, 256, 0, stream>>>(Ws, Wcat + 1179648, 73728);
  k_convert<<<288, 256, 0, stream>>>(projW, Pb, 73728);
  k_transpose_cvt<<<dim3(72, 24), dim3(32, 8), 0, stream>>>(mixallW, Dt, 768, 2304);
  k_bcat<<<9, 256, 0, stream>>>(bh, bw, bs, bcat);
  k_b2<<<3, 256, 0, stream>>>(projW, mixallb, projb, b2);

  // W2 = P . D : (768 x 2304), K=768
  k_gemm256<3><<<3 * 9, 512, 0, stream>>>(Pb, Dt, nullptr, W2, nullptr, nullptr,
                                          nullptr, 2304, 768);
  // [h|w|s] = gelu(x @ [Wh|Ww|Ws]^T + bcat)   (M x 2304, K=768)
  k_gemm256<0><<<98 * 9, 512, 0, stream>>>(xb, Wcat, bcat, hws, nullptr, nullptr,
                                           nullptr, 2304, 768);
  k_pool<<<512, 256, 0, stream>>>(hws, h2v, w2v, s1v);
  k_gates<<<512, 256, 0, stream>>>(h2v, w2v, s1v, convH_w, convH_b, convH2_k,
                                   convH2_b, mixhw_k, mixhw_b, mixhw2_k, mixhw2_b,
                                   mixhws_k, mixhws_b, mixhws2_k, mixhws2_b,
                                   linHW, linHb, linWW, linWb, gh, ghw, gc);
  k_gapply<<<28224, 256, 0, stream>>>(hws, gh, ghw, gc);
  // out = g0*(cat @ W2^T + b2) + g1*x   (M x 768, K=2304, fp32 out)
  k_gemm256<2><<<98 * 3, 512, 0, stream>>>(hws, W2, b2, nullptr, out, x,
                                           gatew, 768, 2304);
}